// Round 1
// baseline (14647.894 us; speedup 1.0000x reference)
//
#include <hip/hip_runtime.h>
#include <cstddef>

// OwnVanillaRNN: x[256,512,64] fp32, Wx[512,64], bx[512], Wh[512,512], bh[512],
// Wy[64,512], by[64] -> y[256,64] fp32.
//
// R1 baseline: one block per batch element (256 blocks = 256 CUs), 512 threads
// (one per hidden unit). Wx row lives in registers for the whole sequence;
// h lives in LDS (broadcast reads); Wh rows are streamed from L2 every step
// (the known 1 MB/step/CU replication cost -> ~3.9 ms L2-bound floor).

constexpr int BATCH = 256;
constexpr int SEQ   = 512;
constexpr int IN    = 64;
constexpr int HID   = 512;
constexpr int OUT   = 64;

__global__ __launch_bounds__(HID, 1)
void rnn_fused(const float* __restrict__ x,  const float* __restrict__ Wx,
               const float* __restrict__ bx, const float* __restrict__ Wh,
               const float* __restrict__ bh, const float* __restrict__ Wy,
               const float* __restrict__ by, float* __restrict__ y) {
    __shared__ __align__(16) float hs[HID];  // current hidden state
    __shared__ __align__(16) float xs[IN];   // current x row

    const int b = blockIdx.x;
    const int o = threadIdx.x;   // hidden unit owned by this thread

    // Pin this unit's Wx row (64 floats) in registers for all 512 steps.
    float4 wx[IN / 4];
    {
        const float4* wxrow = reinterpret_cast<const float4*>(Wx + (size_t)o * IN);
        #pragma unroll
        for (int q = 0; q < IN / 4; ++q) wx[q] = wxrow[q];
    }

    const float  bsum  = bx[o] + bh[o];
    const float* xb    = x + (size_t)b * SEQ * IN;
    const float4* whrow = reinterpret_cast<const float4*>(Wh + (size_t)o * HID);

    hs[o] = 0.0f;

    for (int t = 0; t < SEQ; ++t) {
        if (o < IN) xs[o] = xb[(size_t)t * IN + o];
        __syncthreads();  // xs staged; hs write from previous step visible

        float acc = bsum;

        // Input projection: registers x LDS-broadcast.
        {
            const float4* xv = reinterpret_cast<const float4*>(xs);
            #pragma unroll
            for (int q = 0; q < IN / 4; ++q) {
                float4 w = wx[q], v = xv[q];
                acc += w.x * v.x + w.y * v.y + w.z * v.z + w.w * v.w;
            }
        }

        // Recurrent matvec: stream Wh row from L2, h from LDS (broadcast).
        {
            const float4* hv = reinterpret_cast<const float4*>(hs);
            #pragma unroll 16
            for (int q = 0; q < HID / 4; ++q) {
                float4 w = whrow[q], v = hv[q];
                acc += w.x * v.x + w.y * v.y + w.z * v.z + w.w * v.w;
            }
        }

        float hn = tanhf(acc);
        __syncthreads();  // everyone done reading hs for this step
        hs[o] = hn;
    }
    __syncthreads();

    // Final projection y = hT @ Wy^T + by (threads 0..63 only).
    if (o < OUT) {
        float acc = by[o];
        const float4* wyrow = reinterpret_cast<const float4*>(Wy + (size_t)o * HID);
        const float4* hv    = reinterpret_cast<const float4*>(hs);
        #pragma unroll 16
        for (int q = 0; q < HID / 4; ++q) {
            float4 w = wyrow[q], v = hv[q];
            acc += w.x * v.x + w.y * v.y + w.z * v.z + w.w * v.w;
        }
        y[(size_t)b * OUT + o] = acc;
    }
}

extern "C" void kernel_launch(void* const* d_in, const int* in_sizes, int n_in,
                              void* d_out, int out_size, void* d_ws, size_t ws_size,
                              hipStream_t stream) {
    const float* x  = (const float*)d_in[0];
    const float* Wx = (const float*)d_in[1];
    const float* bx = (const float*)d_in[2];
    const float* Wh = (const float*)d_in[3];
    const float* bh = (const float*)d_in[4];
    const float* Wy = (const float*)d_in[5];
    const float* by = (const float*)d_in[6];
    float* y = (float*)d_out;

    hipLaunchKernelGGL(rnn_fused, dim3(BATCH), dim3(HID), 0, stream,
                       x, Wx, bx, Wh, bh, Wy, by, y);
}

// Round 2
// 3625.235 us; speedup vs baseline: 4.0405x; 4.0405x over previous
//
#include <hip/hip_runtime.h>
#include <cstddef>
#include <cstdint>

// OwnVanillaRNN R2: coalesced + bf16-compressed recurrent weights.
//
// Layout fix: P[j2][o] = pack(bf16(Wh[o][2*j2]) lo, bf16(Wh[o][2*j2+1]) hi),
// stored in d_ws (512 KB). Main loop: lane o reads P[j2][o] -> consecutive
// lanes read consecutive dwords (256 B/wave-instr, ~4 lines vs 64 before).
// h stays fp32 in LDS (broadcast reads); accumulation fp32; only Wh is bf16.

constexpr int BATCH = 256;
constexpr int SEQ   = 512;
constexpr int IN    = 64;
constexpr int HID   = 512;
constexpr int OUT   = 64;

__device__ __forceinline__ uint32_t f2bf_rne(float f) {
    uint32_t u = __float_as_uint(f);
    return (u + 0x7FFFu + ((u >> 16) & 1u)) >> 16;
}

// Transpose+convert Wh[512][512] fp32 -> P[256][512] dwords (bf16x2 along j).
// 32 blocks x 256 threads; coalesced reads and writes via LDS tile.
__global__ __launch_bounds__(256, 1)
void prep_wh(const float* __restrict__ Wh, uint32_t* __restrict__ P) {
    __shared__ float tile[64][130];  // +2 pad: breaks stride-128 bank aliasing
    const int J = (blockIdx.x & 3) * 64;   // j2-tile origin (4 tiles -> 256)
    const int O = (blockIdx.x >> 2) * 64;  // o-tile origin  (8 tiles -> 512)
    const int t = threadIdx.x;

    // Read 64 rows (o = O..O+63) x 128 floats (cols 2J..2J+127), coalesced.
    const float4* Wh4 = reinterpret_cast<const float4*>(Wh);  // row = 128 f4
    for (int k = t; k < 64 * 32; k += 256) {
        const int r = k >> 5, c = k & 31;
        float4 v = Wh4[(size_t)(O + r) * 128 + (J >> 1) + c];
        tile[r][4 * c + 0] = v.x;
        tile[r][4 * c + 1] = v.y;
        tile[r][4 * c + 2] = v.z;
        tile[r][4 * c + 3] = v.w;
    }
    __syncthreads();

    // Write P[(J+j2l)*512 + O+ol], coalesced in ol.
    for (int k = t; k < 64 * 64; k += 256) {
        const int j2l = k >> 6, ol = k & 63;
        const float a = tile[ol][2 * j2l + 0];
        const float b = tile[ol][2 * j2l + 1];
        P[(size_t)(J + j2l) * HID + O + ol] = f2bf_rne(a) | (f2bf_rne(b) << 16);
    }
}

__global__ __launch_bounds__(HID, 1)
void rnn_main(const float* __restrict__ x,  const float* __restrict__ Wx,
              const float* __restrict__ bx, const float* __restrict__ bh,
              const float* __restrict__ Wy, const float* __restrict__ by,
              const uint32_t* __restrict__ P, float* __restrict__ y) {
    __shared__ __align__(16) float hs[HID];
    __shared__ __align__(16) float xs[IN];

    const int b = blockIdx.x;
    const int o = threadIdx.x;

    // Pin Wx row (64 floats) in registers for all 512 steps.
    float4 wx[IN / 4];
    {
        const float4* wxrow = reinterpret_cast<const float4*>(Wx + (size_t)o * IN);
        #pragma unroll
        for (int q = 0; q < IN / 4; ++q) wx[q] = wxrow[q];
    }

    const float  bsum = bx[o] + bh[o];
    const float* xb   = x + (size_t)b * SEQ * IN;
    const uint32_t* Po = P + o;   // column o of the transposed packed weights

    hs[o] = 0.0f;

    for (int t = 0; t < SEQ; ++t) {
        if (o < IN) xs[o] = xb[(size_t)t * IN + o];
        __syncthreads();  // xs staged; hs write from previous step visible

        float acc = bsum;

        // Input projection: registers x LDS-broadcast (fp32).
        {
            const float4* xv = reinterpret_cast<const float4*>(xs);
            #pragma unroll
            for (int q = 0; q < IN / 4; ++q) {
                float4 w = wx[q], v = xv[q];
                acc += w.x * v.x + w.y * v.y + w.z * v.z + w.w * v.w;
            }
        }

        // Recurrent matvec: coalesced bf16x2 weight stream, fp32 h broadcast.
        {
            const float2* h2 = reinterpret_cast<const float2*>(hs);
            #pragma unroll 8
            for (int j2 = 0; j2 < HID / 2; ++j2) {
                const uint32_t w = Po[(size_t)j2 * HID];  // P[j2][o]
                const float2   h = h2[j2];
                const float wlo = __uint_as_float(w << 16);           // Wh[o][2j2]
                const float whi = __uint_as_float(w & 0xFFFF0000u);   // Wh[o][2j2+1]
                acc = fmaf(wlo, h.x, acc);
                acc = fmaf(whi, h.y, acc);
            }
        }

        const float hn = tanhf(acc);
        __syncthreads();  // everyone done reading hs for this step
        hs[o] = hn;
    }
    __syncthreads();

    // Final projection y = hT @ Wy^T + by (threads 0..63, fp32, one-time).
    if (o < OUT) {
        float acc = by[o];
        const float4* wyrow = reinterpret_cast<const float4*>(Wy + (size_t)o * HID);
        const float4* hv    = reinterpret_cast<const float4*>(hs);
        #pragma unroll 16
        for (int q = 0; q < HID / 4; ++q) {
            float4 w = wyrow[q], v = hv[q];
            acc += w.x * v.x + w.y * v.y + w.z * v.z + w.w * v.w;
        }
        y[(size_t)b * OUT + o] = acc;
    }
}

extern "C" void kernel_launch(void* const* d_in, const int* in_sizes, int n_in,
                              void* d_out, int out_size, void* d_ws, size_t ws_size,
                              hipStream_t stream) {
    const float* x  = (const float*)d_in[0];
    const float* Wx = (const float*)d_in[1];
    const float* bx = (const float*)d_in[2];
    const float* Wh = (const float*)d_in[3];
    const float* bh = (const float*)d_in[4];
    const float* Wy = (const float*)d_in[5];
    const float* by = (const float*)d_in[6];
    float* y = (float*)d_out;

    uint32_t* P = (uint32_t*)d_ws;  // 512 KB packed transposed Wh

    hipLaunchKernelGGL(prep_wh, dim3(32), dim3(256), 0, stream, Wh, P);
    hipLaunchKernelGGL(rnn_main, dim3(BATCH), dim3(HID), 0, stream,
                       x, Wx, bx, bh, Wy, by, P, y);
}

// Round 3
// 1578.762 us; speedup vs baseline: 9.2781x; 2.2963x over previous
//
#include <hip/hip_runtime.h>
#include <hip/hip_fp16.h>
#include <cstdint>
#include <cstddef>

// OwnVanillaRNN R3: weight-stationary persistent RNN.
// W~[o] = [Wh[o][0..511] ; Wx[o][0..63]] as f16, packed in 72 groups of 8
// (fragment layout Wt[jg][o][8]). Per CU (one batch/block): 53 groups pinned
// in VGPRs, 19 groups in LDS -- loaded ONCE. Per step: h~=[h;x_t] broadcast
// from LDS (72 b128 reads, wave-uniform) + 19 conflict-free LDS weight reads
// + 288 v_dot2_f32_f16 (fp32 accum). Zero per-step weight traffic from L2.

constexpr int BATCH = 256;
constexpr int SEQ   = 512;
constexpr int IN    = 64;
constexpr int HID   = 512;
constexpr int OUT   = 64;
constexpr int JG_TOT = (HID + IN) / 8;   // 72 groups of 8 f16
constexpr int JG_LDS = 19;               // 19*512*16 B = 152 KB in LDS
constexpr int JG_REG = JG_TOT - JG_LDS;  // 53 groups -> 212 VGPRs/thread

typedef _Float16 half2v __attribute__((ext_vector_type(2)));

__device__ __forceinline__ float fdot2(uint32_t w, uint32_t h, float acc) {
#if __has_builtin(__builtin_amdgcn_fdot2)
    return __builtin_amdgcn_fdot2(__builtin_bit_cast(half2v, w),
                                  __builtin_bit_cast(half2v, h), acc, false);
#else
    __half2 wh = __builtin_bit_cast(__half2, w);
    __half2 hh = __builtin_bit_cast(__half2, h);
    acc = fmaf(__low2float(wh),  __low2float(hh),  acc);
    acc = fmaf(__high2float(wh), __high2float(hh), acc);
    return acc;
#endif
}

__device__ __forceinline__ uint32_t packh2(float lo, float hi) {
    return (uint32_t)__half_as_ushort(__float2half(lo)) |
           ((uint32_t)__half_as_ushort(__float2half(hi)) << 16);
}

// Build Wt[jg][o][8 f16] (uint4 per fragment) from Wh (jg<64) and Wx (jg>=64).
__global__ __launch_bounds__(256, 1)
void prep_w(const float* __restrict__ Wh, const float* __restrict__ Wx,
            uint4* __restrict__ Wt) {
    const int idx = blockIdx.x * 256 + threadIdx.x;  // 72*512 fragments
    const int jg = idx >> 9, o = idx & 511;
    const float* s = (jg < 64) ? (Wh + (size_t)o * HID + jg * 8)
                               : (Wx + (size_t)o * IN + (jg - 64) * 8);
    uint4 d;
    d.x = packh2(s[0], s[1]);
    d.y = packh2(s[2], s[3]);
    d.z = packh2(s[4], s[5]);
    d.w = packh2(s[6], s[7]);
    Wt[idx] = d;
}

__global__ __launch_bounds__(HID, 2)
void rnn_main(const float* __restrict__ x,  const float* __restrict__ bx,
              const float* __restrict__ bh, const float* __restrict__ Wy,
              const float* __restrict__ by, const uint4* __restrict__ Wt,
              float* __restrict__ y) {
    __shared__ uint4  wl[JG_LDS * HID];   // 152 KB: LDS-resident weight groups
    __shared__ __half ht[JG_TOT * 8];     // 1152 B: h~ = [h(512); x_t(64)] f16

    const int b = blockIdx.x;
    const int o = threadIdx.x;

    // ---- one-time: stage LDS weights, pin register weights ----
    for (int g = 0; g < JG_LDS; ++g)          // coalesced global, contiguous LDS
        wl[g * HID + o] = Wt[(size_t)g * HID + o];
    uint4 wr[JG_REG];
    #pragma unroll
    for (int r = 0; r < JG_REG; ++r)
        wr[r] = Wt[(size_t)(JG_LDS + r) * HID + o];

    const float  bsum = bx[o] + bh[o];
    const float* xb   = x + (size_t)b * SEQ * IN;

    ht[o] = __float2half(0.0f);  // h0 = 0 (o covers all 512 h slots)

    for (int t = 0; t < SEQ; ++t) {
        if (o < IN) ht[HID + o] = __float2half(xb[t * IN + o]);
        __syncthreads();  // h~ (h from prev step + x_t) fully staged

        const uint4* hb = (const uint4*)ht;
        float a0 = 0.f, a1 = 0.f, a2 = 0.f, a3 = 0.f;

        #pragma unroll
        for (int g = 0; g < JG_LDS; ++g) {
            const uint4 hv = hb[g];            // broadcast (wave-uniform)
            const uint4 wv = wl[g * HID + o];  // wave-contiguous 1024 B
            a0 = fdot2(wv.x, hv.x, a0);
            a1 = fdot2(wv.y, hv.y, a1);
            a2 = fdot2(wv.z, hv.z, a2);
            a3 = fdot2(wv.w, hv.w, a3);
        }
        #pragma unroll
        for (int r = 0; r < JG_REG; ++r) {
            const uint4 hv = hb[JG_LDS + r];   // broadcast
            a0 = fdot2(wr[r].x, hv.x, a0);
            a1 = fdot2(wr[r].y, hv.y, a1);
            a2 = fdot2(wr[r].z, hv.z, a2);
            a3 = fdot2(wr[r].w, hv.w, a3);
        }

        float acc = bsum + (a0 + a1) + (a2 + a3);
        // fast tanh: 1 - 2/(e^{2x}+1); clamp keeps exp finite (tanh(15)==1 in f32)
        acc = fminf(fmaxf(acc, -15.f), 15.f);
        const float e  = __expf(2.f * acc);
        const float hn = 1.f - 2.f * __builtin_amdgcn_rcpf(e + 1.f);

        __syncthreads();  // all reads of ht for this step done
        ht[o] = __float2half(hn);
    }
    __syncthreads();

    // ---- epilogue: y = hT @ Wy^T + by (threads 0..63, one-time) ----
    if (o < OUT) {
        float acc = by[o];
        const float* wy = Wy + (size_t)o * HID;
        #pragma unroll 16
        for (int j = 0; j < HID; ++j)
            acc = fmaf(wy[j], __half2float(ht[j]), acc);
        y[(size_t)b * OUT + o] = acc;
    }
}

extern "C" void kernel_launch(void* const* d_in, const int* in_sizes, int n_in,
                              void* d_out, int out_size, void* d_ws, size_t ws_size,
                              hipStream_t stream) {
    const float* x  = (const float*)d_in[0];
    const float* Wx = (const float*)d_in[1];
    const float* bx = (const float*)d_in[2];
    const float* Wh = (const float*)d_in[3];
    const float* bh = (const float*)d_in[4];
    const float* Wy = (const float*)d_in[5];
    const float* by = (const float*)d_in[6];
    float* y = (float*)d_out;

    uint4* Wt = (uint4*)d_ws;  // 72*512*16 B = 576 KB packed f16 fragments

    hipLaunchKernelGGL(prep_w, dim3(JG_TOT * HID / 256), dim3(256), 0, stream,
                       Wh, Wx, Wt);
    hipLaunchKernelGGL(rnn_main, dim3(BATCH), dim3(HID), 0, stream,
                       x, bx, bh, Wy, by, Wt, y);
}

// Round 4
// 1570.457 us; speedup vs baseline: 9.3272x; 1.0053x over previous
//
#include <hip/hip_runtime.h>
#include <hip/hip_fp16.h>
#include <cstdint>
#include <cstddef>

// OwnVanillaRNN R4: weight-stationary persistent RNN, spill fixed.
// R3 lesson: launch_bounds(512,2) is only a MINIMUM waves/EU -> allocator
// targeted 128 VGPRs and spilled the 212-reg weight array to scratch
// (57 GB of scratch reads = the whole 1.7 ms). Fix: amdgpu_waves_per_eu(2,2)
// pins exactly 2 waves/EU -> 256 VGPRs/thread. Also prefetch x_{t+1} during
// step t's compute to hide the per-step global-load latency.

constexpr int BATCH = 256;
constexpr int SEQ   = 512;
constexpr int IN    = 64;
constexpr int HID   = 512;
constexpr int OUT   = 64;
constexpr int JG_TOT = (HID + IN) / 8;   // 72 groups of 8 f16
constexpr int JG_LDS = 19;               // 19*512*16 B = 152 KB in LDS
constexpr int JG_REG = JG_TOT - JG_LDS;  // 53 groups -> 212 VGPRs/thread

typedef _Float16 half2v __attribute__((ext_vector_type(2)));

__device__ __forceinline__ float fdot2(uint32_t w, uint32_t h, float acc) {
#if __has_builtin(__builtin_amdgcn_fdot2)
    return __builtin_amdgcn_fdot2(__builtin_bit_cast(half2v, w),
                                  __builtin_bit_cast(half2v, h), acc, false);
#else
    __half2 wh = __builtin_bit_cast(__half2, w);
    __half2 hh = __builtin_bit_cast(__half2, h);
    acc = fmaf(__low2float(wh),  __low2float(hh),  acc);
    acc = fmaf(__high2float(wh), __high2float(hh), acc);
    return acc;
#endif
}

__device__ __forceinline__ uint32_t packh2(float lo, float hi) {
    return (uint32_t)__half_as_ushort(__float2half(lo)) |
           ((uint32_t)__half_as_ushort(__float2half(hi)) << 16);
}

// Build Wt[jg][o][8 f16] (uint4 per fragment) from Wh (jg<64) and Wx (jg>=64).
__global__ __launch_bounds__(256, 1)
void prep_w(const float* __restrict__ Wh, const float* __restrict__ Wx,
            uint4* __restrict__ Wt) {
    const int idx = blockIdx.x * 256 + threadIdx.x;  // 72*512 fragments
    const int jg = idx >> 9, o = idx & 511;
    const float* s = (jg < 64) ? (Wh + (size_t)o * HID + jg * 8)
                               : (Wx + (size_t)o * IN + (jg - 64) * 8);
    uint4 d;
    d.x = packh2(s[0], s[1]);
    d.y = packh2(s[2], s[3]);
    d.z = packh2(s[4], s[5]);
    d.w = packh2(s[6], s[7]);
    Wt[idx] = d;
}

__global__ __launch_bounds__(HID)
__attribute__((amdgpu_waves_per_eu(2, 2)))
void rnn_main(const float* __restrict__ x,  const float* __restrict__ bx,
              const float* __restrict__ bh, const float* __restrict__ Wy,
              const float* __restrict__ by, const uint4* __restrict__ Wt,
              float* __restrict__ y) {
    __shared__ uint4 wl[JG_LDS * HID];               // 152 KB weight groups
    __shared__ __align__(16) __half ht[JG_TOT * 8];  // h~ = [h(512); x_t(64)]

    const int b = blockIdx.x;
    const int o = threadIdx.x;

    // ---- one-time: stage LDS weights, pin register weights ----
    for (int g = 0; g < JG_LDS; ++g)          // coalesced global, contiguous LDS
        wl[g * HID + o] = Wt[(size_t)g * HID + o];
    uint4 wr[JG_REG];
    #pragma unroll
    for (int r = 0; r < JG_REG; ++r)
        wr[r] = Wt[(size_t)(JG_LDS + r) * HID + o];

    const float  bsum = bx[o] + bh[o];
    const float* xb   = x + (size_t)b * SEQ * IN;

    ht[o] = __float2half(0.0f);          // h0 = 0
    float xv = (o < IN) ? xb[o] : 0.0f;  // prefetched x_0

    for (int t = 0; t < SEQ; ++t) {
        if (o < IN) ht[HID + o] = __float2half(xv);
        __syncthreads();  // h~ (prev h + x_t) fully staged

        // Prefetch x_{t+1}: latency hides under this step's compute.
        if (o < IN && t + 1 < SEQ) xv = xb[(t + 1) * IN + o];

        const uint4* hb = (const uint4*)ht;
        float a0 = 0.f, a1 = 0.f, a2 = 0.f, a3 = 0.f;

        #pragma unroll 4
        for (int g = 0; g < JG_LDS; ++g) {
            const uint4 hv = hb[g];            // broadcast (wave-uniform)
            const uint4 wv = wl[g * HID + o];  // wave-contiguous 1024 B
            a0 = fdot2(wv.x, hv.x, a0);
            a1 = fdot2(wv.y, hv.y, a1);
            a2 = fdot2(wv.z, hv.z, a2);
            a3 = fdot2(wv.w, hv.w, a3);
        }
        #pragma unroll
        for (int r = 0; r < JG_REG; ++r) {     // static indices: stays in regs
            const uint4 hv = hb[JG_LDS + r];   // broadcast
            a0 = fdot2(wr[r].x, hv.x, a0);
            a1 = fdot2(wr[r].y, hv.y, a1);
            a2 = fdot2(wr[r].z, hv.z, a2);
            a3 = fdot2(wr[r].w, hv.w, a3);
        }

        float acc = bsum + (a0 + a1) + (a2 + a3);
        // fast tanh: 1 - 2/(e^{2x}+1); clamp keeps exp finite
        acc = fminf(fmaxf(acc, -15.f), 15.f);
        const float e  = __expf(2.f * acc);
        const float hn = 1.f - 2.f * __builtin_amdgcn_rcpf(e + 1.f);

        __syncthreads();  // all reads of ht for this step done
        ht[o] = __float2half(hn);
    }
    __syncthreads();

    // ---- epilogue: y = hT @ Wy^T + by (threads 0..63, one-time) ----
    if (o < OUT) {
        float acc = by[o];
        const float* wy = Wy + (size_t)o * HID;
        #pragma unroll 16
        for (int j = 0; j < HID; ++j)
            acc = fmaf(wy[j], __half2float(ht[j]), acc);
        y[(size_t)b * OUT + o] = acc;
    }
}

extern "C" void kernel_launch(void* const* d_in, const int* in_sizes, int n_in,
                              void* d_out, int out_size, void* d_ws, size_t ws_size,
                              hipStream_t stream) {
    const float* x  = (const float*)d_in[0];
    const float* Wx = (const float*)d_in[1];
    const float* bx = (const float*)d_in[2];
    const float* Wh = (const float*)d_in[3];
    const float* bh = (const float*)d_in[4];
    const float* Wy = (const float*)d_in[5];
    const float* by = (const float*)d_in[6];
    float* y = (float*)d_out;

    uint4* Wt = (uint4*)d_ws;  // 72*512*16 B = 576 KB packed f16 fragments

    hipLaunchKernelGGL(prep_w, dim3(JG_TOT * HID / 256), dim3(256), 0, stream,
                       Wh, Wx, Wt);
    hipLaunchKernelGGL(rnn_main, dim3(BATCH), dim3(HID), 0, stream,
                       x, bx, bh, Wy, by, Wt, y);
}

// Round 5
// 1540.952 us; speedup vs baseline: 9.5057x; 1.0191x over previous
//
#include <hip/hip_runtime.h>
#include <hip/hip_fp16.h>
#include <cstdint>
#include <cstddef>

// OwnVanillaRNN R5: weight-stationary persistent RNN, spill fixed for real.
// R3/R4 lesson: `uint4 wr[53]` is an 848 B alloca; SROA runs BEFORE full
// unroll, so it stays scratch-resident no matter what occupancy attrs say
// (57 GB of scratch re-reads = the whole 1.7 ms; VGPR_Count stuck at 128).
// Fix: 53 individually NAMED uint4 locals (X-macro) -> SSA from the frontend,
// no alloca, nothing to scratch. waves_per_eu(2,2) + launch_bounds(512,2)
// give the 256-VGPR budget (2 waves/EU; LDS already caps us at 1 block/CU).

constexpr int BATCH = 256;
constexpr int SEQ   = 512;
constexpr int IN    = 64;
constexpr int HID   = 512;
constexpr int OUT   = 64;
constexpr int JG_TOT = (HID + IN) / 8;   // 72 groups of 8 f16
constexpr int JG_LDS = 19;               // 19*512*16 B = 152 KB in LDS
constexpr int JG_REG = JG_TOT - JG_LDS;  // 53 groups -> 212 named VGPRs

typedef _Float16 half2v __attribute__((ext_vector_type(2)));

__device__ __forceinline__ float fdot2(uint32_t w, uint32_t h, float acc) {
#if __has_builtin(__builtin_amdgcn_fdot2)
    return __builtin_amdgcn_fdot2(__builtin_bit_cast(half2v, w),
                                  __builtin_bit_cast(half2v, h), acc, false);
#else
    __half2 wh = __builtin_bit_cast(__half2, w);
    __half2 hh = __builtin_bit_cast(__half2, h);
    acc = fmaf(__low2float(wh),  __low2float(hh),  acc);
    acc = fmaf(__high2float(wh), __high2float(hh), acc);
    return acc;
#endif
}

__device__ __forceinline__ uint32_t packh2(float lo, float hi) {
    return (uint32_t)__half_as_ushort(__float2half(lo)) |
           ((uint32_t)__half_as_ushort(__float2half(hi)) << 16);
}

// Build Wt[jg][o][8 f16] (uint4 per fragment) from Wh (jg<64) and Wx (jg>=64).
__global__ __launch_bounds__(256, 1)
void prep_w(const float* __restrict__ Wh, const float* __restrict__ Wx,
            uint4* __restrict__ Wt) {
    const int idx = blockIdx.x * 256 + threadIdx.x;  // 72*512 fragments
    const int jg = idx >> 9, o = idx & 511;
    const float* s = (jg < 64) ? (Wh + (size_t)o * HID + jg * 8)
                               : (Wx + (size_t)o * IN + (jg - 64) * 8);
    uint4 d;
    d.x = packh2(s[0], s[1]);
    d.y = packh2(s[2], s[3]);
    d.z = packh2(s[4], s[5]);
    d.w = packh2(s[6], s[7]);
    Wt[idx] = d;
}

// X-macro over the 53 register-resident weight groups.
#define RG_LIST(M) \
  M(0)  M(1)  M(2)  M(3)  M(4)  M(5)  M(6)  M(7)  M(8)  M(9)  \
  M(10) M(11) M(12) M(13) M(14) M(15) M(16) M(17) M(18) M(19) \
  M(20) M(21) M(22) M(23) M(24) M(25) M(26) M(27) M(28) M(29) \
  M(30) M(31) M(32) M(33) M(34) M(35) M(36) M(37) M(38) M(39) \
  M(40) M(41) M(42) M(43) M(44) M(45) M(46) M(47) M(48) M(49) \
  M(50) M(51) M(52)

__global__ __launch_bounds__(HID, 2)
__attribute__((amdgpu_waves_per_eu(2, 2)))
void rnn_main(const float* __restrict__ x,  const float* __restrict__ bx,
              const float* __restrict__ bh, const float* __restrict__ Wy,
              const float* __restrict__ by, const uint4* __restrict__ Wt,
              float* __restrict__ y) {
    __shared__ uint4 wl[JG_LDS * HID];               // 152 KB weight groups
    __shared__ __align__(16) __half ht[JG_TOT * 8];  // h~ = [h(512); x_t(64)]

    const int b = blockIdx.x;
    const int o = threadIdx.x;

    // ---- one-time: stage LDS weights ----
    for (int g = 0; g < JG_LDS; ++g)          // coalesced global, contiguous LDS
        wl[g * HID + o] = Wt[(size_t)g * HID + o];

    // ---- one-time: pin 53 weight groups in NAMED registers (SSA, no alloca) ----
    const uint4* Wto = Wt + o;
#define DECL_W(n) uint4 w##n = Wto[(size_t)(JG_LDS + (n)) * HID];
    RG_LIST(DECL_W)
#undef DECL_W

    const float  bsum = bx[o] + bh[o];
    const float* xb   = x + (size_t)b * SEQ * IN;

    ht[o] = __float2half(0.0f);          // h0 = 0
    float xv = (o < IN) ? xb[o] : 0.0f;  // prefetched x_0

    for (int t = 0; t < SEQ; ++t) {
        if (o < IN) ht[HID + o] = __float2half(xv);
        __syncthreads();  // h~ (prev h + x_t) fully staged

        // Prefetch x_{t+1}: latency hides under this step's compute.
        if (o < IN && t + 1 < SEQ) xv = xb[(t + 1) * IN + o];

        const uint4* hb = (const uint4*)ht;
        float a0 = 0.f, a1 = 0.f, a2 = 0.f, a3 = 0.f;

        // LDS-resident groups: broadcast h + wave-contiguous weight reads.
        #pragma unroll 4
        for (int g = 0; g < JG_LDS; ++g) {
            const uint4 hv = hb[g];
            const uint4 wv = wl[g * HID + o];
            a0 = fdot2(wv.x, hv.x, a0);
            a1 = fdot2(wv.y, hv.y, a1);
            a2 = fdot2(wv.z, hv.z, a2);
            a3 = fdot2(wv.w, hv.w, a3);
        }

        // Register-resident groups: straight-line named-register MACs.
#define MAC_W(n) { const uint4 hv = hb[JG_LDS + (n)];      \
        a0 = fdot2(w##n.x, hv.x, a0);                      \
        a1 = fdot2(w##n.y, hv.y, a1);                      \
        a2 = fdot2(w##n.z, hv.z, a2);                      \
        a3 = fdot2(w##n.w, hv.w, a3); }
        RG_LIST(MAC_W)
#undef MAC_W

        float acc = bsum + (a0 + a1) + (a2 + a3);
        // fast tanh: 1 - 2/(e^{2x}+1); clamp keeps exp finite
        acc = fminf(fmaxf(acc, -15.f), 15.f);
        const float e  = __expf(2.f * acc);
        const float hn = 1.f - 2.f * __builtin_amdgcn_rcpf(e + 1.f);

        __syncthreads();  // all reads of ht for this step done
        ht[o] = __float2half(hn);
    }
    __syncthreads();

    // ---- epilogue: y = hT @ Wy^T + by (threads 0..63, one-time) ----
    if (o < OUT) {
        float acc = by[o];
        const float* wy = Wy + (size_t)o * HID;
        #pragma unroll 16
        for (int j = 0; j < HID; ++j)
            acc = fmaf(wy[j], __half2float(ht[j]), acc);
        y[(size_t)b * OUT + o] = acc;
    }
}

extern "C" void kernel_launch(void* const* d_in, const int* in_sizes, int n_in,
                              void* d_out, int out_size, void* d_ws, size_t ws_size,
                              hipStream_t stream) {
    const float* x  = (const float*)d_in[0];
    const float* Wx = (const float*)d_in[1];
    const float* bx = (const float*)d_in[2];
    const float* Wh = (const float*)d_in[3];
    const float* bh = (const float*)d_in[4];
    const float* Wy = (const float*)d_in[5];
    const float* by = (const float*)d_in[6];
    float* y = (float*)d_out;

    uint4* Wt = (uint4*)d_ws;  // 72*512*16 B = 576 KB packed f16 fragments

    hipLaunchKernelGGL(prep_w, dim3(JG_TOT * HID / 256), dim3(256), 0, stream,
                       Wh, Wx, Wt);
    hipLaunchKernelGGL(rnn_main, dim3(BATCH), dim3(HID), 0, stream,
                       x, bx, bh, Wy, by, Wt, y);
}

// Round 7
// 993.936 us; speedup vs baseline: 14.7373x; 1.5504x over previous
//
#include <hip/hip_runtime.h>
#include <hip/hip_fp16.h>
#include <cstdint>
#include <cstddef>

// OwnVanillaRNN R7 (= R6 + compile fix): persistent RNN, redecomposed so the
// register need FITS the 128-VGPR budget the allocator enforces (R3-R5: three
// pinning attempts, all flat at 128 regs / 1.6 ms -> stop fighting it).
//   T=1024 threads/block, thread = (out-pair g, k-slice s): outputs {2g,2g+1},
//   dims [144s,144s+144) of h~=[h;x_t]. Per-thread weights = 2x144 f16 =
//   36 uint4: 27 in registers (108 VGPR) + 9 in LDS (144 KB). 4-way K-split
//   reduced IN-REGISTER via quad DPP butterfly (lanes of a quad = the 4
//   slices of one out-pair) -> no reduction LDS, ONE barrier/step
//   (double-buffered h). h-broadcasts halve (each 16B fragment feeds 8 dot2).
// R6 compile fix: DPP ctrl must be an integer-constant expression ->
// template<int CTRL> instead of a runtime arg.

constexpr int BATCH = 256;
constexpr int SEQ   = 512;
constexpr int IN    = 64;
constexpr int HID   = 512;
constexpr int OUT   = 64;
constexpr int T     = 1024;        // threads per block
constexpr int DTOT  = HID + IN;    // 576
constexpr int NS    = 4;           // k-slices
constexpr int DSL   = DTOT / NS;   // 144 dims per slice (288 B: 16B aligned)
constexpr int FR    = DSL / 8;     // 18 fragments of 8 f16 per (out,slice)
constexpr int NREG  = 27;          // frags in registers per thread
constexpr int NLDS  = 9;           // frags in LDS per thread (9*1024*16B=144KB)

typedef _Float16 half2v __attribute__((ext_vector_type(2)));

__device__ __forceinline__ float fdot2(uint32_t w, uint32_t h, float acc) {
    return __builtin_amdgcn_fdot2(__builtin_bit_cast(half2v, w),
                                  __builtin_bit_cast(half2v, h), acc, false);
}
__device__ __forceinline__ uint32_t packh2(float lo, float hi) {
    return (uint32_t)__half_as_ushort(__float2half(lo)) |
           ((uint32_t)__half_as_ushort(__float2half(hi)) << 16);
}
// quad_perm DPP add: CTRL=0xB1 -> [1,0,3,2] (xor1), 0x4E -> [2,3,0,1] (xor2)
template <int CTRL>
__device__ __forceinline__ float dpp_add(float v) {
    int i = __builtin_bit_cast(int, v);
    int p = __builtin_amdgcn_update_dpp(i, i, CTRL, 0xF, 0xF, false);
    return v + __builtin_bit_cast(float, p);
}

// Repack [Wh | Wx] f32 -> per-thread f16 fragments.
// Thread t = (g = t>>2, s = t&3). Frag k of 36: k<18 -> (out 2g,  dim 144s+8k)
//                                 k>=18 -> (out 2g+1, dim 144s+8(k-18))
// k<27 -> Wreg[k][t] (registers); k>=27 -> Wlds[k-27][t] (LDS-staged).
__global__ __launch_bounds__(256, 1)
void prep_w(const float* __restrict__ Wh, const float* __restrict__ Wx,
            uint4* __restrict__ Wreg, uint4* __restrict__ Wlds) {
    const int idx = blockIdx.x * 256 + threadIdx.x;  // 36*1024 fragments
    const int k = idx >> 10, t = idx & (T - 1);
    const int g = t >> 2, s = t & 3;
    const int o = (k < FR) ? 2 * g : 2 * g + 1;
    const int m = (k < FR) ? k : k - FR;
    const int j = DSL * s + 8 * m;   // fragment never straddles the 512 line
    const float* src = (j < HID) ? (Wh + (size_t)o * HID + j)
                                 : (Wx + (size_t)o * IN + (j - HID));
    uint4 d;
    d.x = packh2(src[0], src[1]);
    d.y = packh2(src[2], src[3]);
    d.z = packh2(src[4], src[5]);
    d.w = packh2(src[6], src[7]);
    if (k < NREG) Wreg[(size_t)k * T + t] = d;
    else          Wlds[(size_t)(k - NREG) * T + t] = d;
}

#define WREG_LIST(M) \
  M(0)  M(1)  M(2)  M(3)  M(4)  M(5)  M(6)  M(7)  M(8)  \
  M(9)  M(10) M(11) M(12) M(13) M(14) M(15) M(16) M(17) \
  M(18) M(19) M(20) M(21) M(22) M(23) M(24) M(25) M(26)

__global__ __launch_bounds__(T)
void rnn_main(const float* __restrict__ x,  const float* __restrict__ bx,
              const float* __restrict__ bh, const float* __restrict__ Wy,
              const float* __restrict__ by, const uint4* __restrict__ Wreg,
              const uint4* __restrict__ Wldg, float* __restrict__ y) {
    __shared__ uint4 wl[NLDS * T];                   // 144 KB weights
    __shared__ __align__(16) __half hb2[2][DTOT];    // double-buffered h~

    const int b = blockIdx.x, t = threadIdx.x;
    const int g = t >> 2, s = t & 3;

    // ---- one-time staging ----
    #pragma unroll
    for (int k = 0; k < NLDS; ++k) wl[k * T + t] = Wldg[(size_t)k * T + t];

#define DECL_W(n) uint4 w##n = Wreg[(size_t)(n) * T + t];
    WREG_LIST(DECL_W)
#undef DECL_W

    const float bb0 = bx[2 * g]     + bh[2 * g];
    const float bb1 = bx[2 * g + 1] + bh[2 * g + 1];
    const float* xb = x + (size_t)b * SEQ * IN;

    if (t < HID) hb2[0][t] = __float2half(0.0f);        // h0 = 0
    if (t < IN)  hb2[0][HID + t] = __float2half(xb[t]); // x_0
    float xv = (t < IN) ? xb[IN + t] : 0.0f;            // x_1 prefetched
    __syncthreads();

    for (int tt = 0; tt < SEQ; ++tt) {
        const int c = tt & 1;
        const uint4* hb = (const uint4*)(&hb2[c][DSL * s]);  // this slice's h~
        float a0 = 0.f, a1 = 0.f;

        // frags 0..8: both outs' weights in registers
#define MACR(i, j) { const uint4 hv = hb[i];                          \
        a0 = fdot2(w##i.x, hv.x, a0); a0 = fdot2(w##i.y, hv.y, a0);   \
        a0 = fdot2(w##i.z, hv.z, a0); a0 = fdot2(w##i.w, hv.w, a0);   \
        a1 = fdot2(w##j.x, hv.x, a1); a1 = fdot2(w##j.y, hv.y, a1);   \
        a1 = fdot2(w##j.z, hv.z, a1); a1 = fdot2(w##j.w, hv.w, a1); }
        MACR(0,18) MACR(1,19) MACR(2,20) MACR(3,21) MACR(4,22)
        MACR(5,23) MACR(6,24) MACR(7,25) MACR(8,26)
#undef MACR
        // frags 9..17: out0 weights in registers, out1 weights from LDS
#define MACL(i, k) { const uint4 hv = hb[i];                          \
        const uint4 wv = wl[(k) * T + t];                             \
        a0 = fdot2(w##i.x, hv.x, a0); a0 = fdot2(w##i.y, hv.y, a0);   \
        a0 = fdot2(w##i.z, hv.z, a0); a0 = fdot2(w##i.w, hv.w, a0);   \
        a1 = fdot2(wv.x, hv.x, a1);   a1 = fdot2(wv.y, hv.y, a1);     \
        a1 = fdot2(wv.z, hv.z, a1);   a1 = fdot2(wv.w, hv.w, a1); }
        MACL(9,0)  MACL(10,1) MACL(11,2) MACL(12,3) MACL(13,4)
        MACL(14,5) MACL(15,6) MACL(16,7) MACL(17,8)
#undef MACL

        // 4-way K-reduce inside each quad (lanes = the 4 slices of this pair)
        a0 = dpp_add<0xB1>(a0); a0 = dpp_add<0x4E>(a0);
        a1 = dpp_add<0xB1>(a1); a1 = dpp_add<0x4E>(a1);

        if (s == 0) {
            float z0 = a0 + bb0, z1 = a1 + bb1;
            z0 = fminf(fmaxf(z0, -15.f), 15.f);
            z1 = fminf(fmaxf(z1, -15.f), 15.f);
            const float e0 = __expf(2.f * z0), e1 = __expf(2.f * z1);
            const float h0 = 1.f - 2.f * __builtin_amdgcn_rcpf(e0 + 1.f);
            const float h1 = 1.f - 2.f * __builtin_amdgcn_rcpf(e1 + 1.f);
            ((uint32_t*)hb2[c ^ 1])[g] = packh2(h0, h1);  // outs 2g,2g+1
        }
        if (t < IN) {
            hb2[c ^ 1][HID + t] = __float2half(xv);       // x_{tt+1}
            if (tt + 2 < SEQ) xv = xb[(size_t)(tt + 2) * IN + t];
        }
        __syncthreads();  // next buffer fully staged; prev buffer reads done
    }

    // ---- epilogue: y = h_T @ Wy^T + by (final h is in buffer 0) ----
    if (t < OUT) {
        float acc = by[t];
        const float* wy = Wy + (size_t)t * HID;
        #pragma unroll 8
        for (int j = 0; j < HID; ++j)
            acc = fmaf(wy[j], __half2float(hb2[0][j]), acc);
        y[(size_t)b * OUT + t] = acc;
    }
}

extern "C" void kernel_launch(void* const* d_in, const int* in_sizes, int n_in,
                              void* d_out, int out_size, void* d_ws, size_t ws_size,
                              hipStream_t stream) {
    const float* x  = (const float*)d_in[0];
    const float* Wx = (const float*)d_in[1];
    const float* bx = (const float*)d_in[2];
    const float* Wh = (const float*)d_in[3];
    const float* bh = (const float*)d_in[4];
    const float* Wy = (const float*)d_in[5];
    const float* by = (const float*)d_in[6];
    float* y = (float*)d_out;

    uint4* Wreg = (uint4*)d_ws;                 // 27*1024*16 = 432 KB
    uint4* Wlds = Wreg + (size_t)NREG * T;      //  9*1024*16 = 144 KB

    hipLaunchKernelGGL(prep_w, dim3(36 * T / 256), dim3(256), 0, stream,
                       Wh, Wx, Wreg, Wlds);
    hipLaunchKernelGGL(rnn_main, dim3(BATCH), dim3(T), 0, stream,
                       x, bx, bh, Wy, by, Wreg, Wlds, y);
}